// Round 2
// baseline (258.295 us; speedup 1.0000x reference)
//
#include <hip/hip_runtime.h>
#include <hip/hip_cooperative_groups.h>

namespace cg = cooperative_groups;

#define NB     50000
#define NB4    12500
#define BATCH  256
#define NCYC   20000
#define GRID_F 782                 // NB4/16 column-tiles; 782*64 >= NB rows covered
#define QSCALE  (127.0f / 3.14159265358979f)
#define DQSCALE (3.14159265358979f / 127.0f)
#define OUTSCALE (1.0f / ((float)NCYC * (float)BATCH))

// Fast atan2: Hastings deg-9 odd minimax on [0,1], max err ~1e-5 rad.
// Quantization step is pi/127 ~ 2.47e-2 rad; ~4e-4 of elements can flip one
// int8 code => ~1e-7 relative error on the final mean. v_rcp_f32 replaces the
// IEEE divide sequence of libm atan2f.
__device__ __forceinline__ float fast_atan2f(float y, float x) {
    const float ax = __builtin_fabsf(x);
    const float ay = __builtin_fabsf(y);
    const float mx = fmaxf(ax, ay);
    const float mn = fminf(ax, ay);
    const float t  = mn * __builtin_amdgcn_rcpf(mx);   // in [0,1]
    const float t2 = t * t;
    float p = fmaf(t2, fmaf(t2, fmaf(t2, fmaf(t2,
                  0.0208351f, -0.0851330f), 0.1801410f), -0.3302995f),
                  0.9998660f);
    p *= t;
    p = (ay > ax) ? (1.57079632679489662f - p) : p;    // swap quadrant
    p = (x < 0.0f) ? (3.14159265358979324f - p) : p;   // left half-plane
    return copysignf(p, y);
}

// ---- single fused cooperative kernel --------------------------------------
// Phase 1: theta->int8 transpose into th[NB][BATCH], row_start precompute,
//          out zeroing.  grid.sync().  Phase 2: per-wave KVL row sums,
//          per-lane accumulation, one scaled atomicAdd per block.
__global__ __launch_bounds__(256, 4) void fused_k(
        const float4* __restrict__ c4, const float4* __restrict__ s4,
        signed char* __restrict__ th, int* __restrict__ row_start,
        const float* __restrict__ signs, const int* __restrict__ inds,
        const int* __restrict__ rows, int E, float* __restrict__ out) {
    __shared__ signed char t[64][68];       // theta tile [b_local][nb_local]
    __shared__ float wsum[4];
    const int u = threadIdx.x;

    if (blockIdx.x == 0 && u == 0) out[0] = 0.0f;

    // ---- phase 1a: row_start[0..NCYC] via parallel binary search ----------
    {
        const int g = blockIdx.x * 256 + u;
        if (g <= NCYC) {
            int lo = 0, hi = E;
            while (lo < hi) { const int m = (lo + hi) >> 1; if (rows[m] < g) lo = m + 1; else hi = m; }
            row_start[g] = lo;
        }
    }

    // ---- phase 1b: theta for this block's 16-wide float4 column, 4 b-tiles -
    const int col4 = u & 15;
    const int brow = u >> 4;
    const int x4   = blockIdx.x * 16 + col4;
    #pragma unroll
    for (int by = 0; by < 4; ++by) {
        const int bb = by * 64;
        if (x4 < NB4) {
            #pragma unroll
            for (int j = 0; j < 4; ++j) {
                const int bl = brow + 16 * j;   // b_local 0..63
                const float4 vc = c4[(size_t)(bb + bl) * NB4 + x4];
                const float4 vs = s4[(size_t)(bb + bl) * NB4 + x4];
                char4 q;
                q.x = (signed char)__float2int_rn(fast_atan2f(vs.x, vc.x) * QSCALE);
                q.y = (signed char)__float2int_rn(fast_atan2f(vs.y, vc.y) * QSCALE);
                q.z = (signed char)__float2int_rn(fast_atan2f(vs.z, vc.z) * QSCALE);
                q.w = (signed char)__float2int_rn(fast_atan2f(vs.w, vc.w) * QSCALE);
                *reinterpret_cast<char4*>(&t[bl][4 * col4]) = q;
            }
        }
        __syncthreads();
        const int g2  = u & 15;                 // char4 group along b
        const int nb0 = u >> 4;                 // 0..15
        #pragma unroll
        for (int j = 0; j < 4; ++j) {
            const int nbl = nb0 + 16 * j;       // 0..63
            const int nb  = blockIdx.x * 64 + nbl;
            if (nb < NB) {
                char4 v;
                v.x = t[4 * g2 + 0][nbl];
                v.y = t[4 * g2 + 1][nbl];
                v.z = t[4 * g2 + 2][nbl];
                v.w = t[4 * g2 + 3][nbl];
                *reinterpret_cast<char4*>(&th[(size_t)nb * BATCH + bb + 4 * g2]) = v;
            }
        }
        __syncthreads();
    }

    cg::this_grid().sync();

    // ---- phase 2: KVL rows, one wave per row, strided ----------------------
    const int wave = u >> 6;
    const int lane = u & 63;
    const int w0   = blockIdx.x * 4 + wave;     // 0..3127
    float acc = 0.f;
    for (int r = w0; r < NCYC; r += 4 * GRID_F) {
        const int start = row_start[r];
        const int end   = row_start[r + 1];
        float a0 = 0.f, a1 = 0.f, a2 = 0.f, a3 = 0.f;
        int e = start;
        for (; e + 2 <= end; e += 2) {
            const int   i0 = inds[e],  i1 = inds[e + 1];
            const float g0 = signs[e] * DQSCALE, g1 = signs[e + 1] * DQSCALE;
            const unsigned int u0 = *reinterpret_cast<const unsigned int*>(&th[(size_t)i0 * BATCH + lane * 4]);
            const unsigned int u1 = *reinterpret_cast<const unsigned int*>(&th[(size_t)i1 * BATCH + lane * 4]);
            a0 += g0 * (float)(signed char)(u0      ) + g1 * (float)(signed char)(u1      );
            a1 += g0 * (float)(signed char)(u0 >>  8) + g1 * (float)(signed char)(u1 >>  8);
            a2 += g0 * (float)(signed char)(u0 >> 16) + g1 * (float)(signed char)(u1 >> 16);
            a3 += g0 * (float)(signed char)(u0 >> 24) + g1 * (float)(signed char)(u1 >> 24);
        }
        if (e < end) {
            const float g0 = signs[e] * DQSCALE;
            const unsigned int u0 = *reinterpret_cast<const unsigned int*>(&th[(size_t)inds[e] * BATCH + lane * 4]);
            a0 += g0 * (float)(signed char)(u0      );
            a1 += g0 * (float)(signed char)(u0 >>  8);
            a2 += g0 * (float)(signed char)(u0 >> 16);
            a3 += g0 * (float)(signed char)(u0 >> 24);
        }
        acc += fabsf(a0) + fabsf(a1) + fabsf(a2) + fabsf(a3);
    }
    #pragma unroll
    for (int off = 32; off > 0; off >>= 1)
        acc += __shfl_down(acc, off, 64);
    if (lane == 0) wsum[wave] = acc;
    __syncthreads();
    if (u == 0)
        atomicAdd(out, (wsum[0] + wsum[1] + wsum[2] + wsum[3]) * OUTSCALE);
}

// ---- fallback (no workspace): direct strided gather -----------------------
__global__ void zero_out_k(float* out) { if (threadIdx.x == 0) out[0] = 0.0f; }

__global__ __launch_bounds__(256) void kvl_fallback_k(
        const float* __restrict__ c, const float* __restrict__ s,
        const float* __restrict__ signs, const int* __restrict__ inds,
        const int* __restrict__ rows, int E, float* __restrict__ out) {
    const int r = blockIdx.x;
    int lo = 0, hi = E;
    while (lo < hi) { const int m = (lo + hi) >> 1; if (rows[m] < r) lo = m + 1; else hi = m; }
    const int start = lo;
    hi = E;
    while (lo < hi) { const int m = (lo + hi) >> 1; if (rows[m] <= r) lo = m + 1; else hi = m; }
    const int end = lo;
    const int tid = threadIdx.x;
    float acc = 0.f;
    for (int e = start; e < end; ++e) {
        const int idx = inds[e];
        const float sg = signs[e];
        acc += atan2f(sg * s[(size_t)tid * NB + idx], c[(size_t)tid * NB + idx]);
    }
    float v = fabsf(acc);
    #pragma unroll
    for (int off = 32; off > 0; off >>= 1)
        v += __shfl_down(v, off, 64);
    __shared__ float wsum[4];
    if ((tid & 63) == 0) wsum[tid >> 6] = v;
    __syncthreads();
    if (tid == 0)
        atomicAdd(out, (wsum[0] + wsum[1] + wsum[2] + wsum[3]) *
                       (1.0f / ((float)NCYC * (float)BATCH)));
}

extern "C" void kernel_launch(void* const* d_in, const int* in_sizes, int n_in,
                              void* d_out, int out_size, void* d_ws, size_t ws_size,
                              hipStream_t stream) {
    const float* c       = (const float*)d_in[0];
    const float* s       = (const float*)d_in[1];
    const float* cysigns = (const float*)d_in[2];
    const int*   cyinds  = (const int*)d_in[3];
    const int*   cyrows  = (const int*)d_in[4];
    int          E       = in_sizes[2];   // 160000
    float* out = (float*)d_out;

    const size_t th_bytes = (size_t)NB * BATCH;           // 12.8 MB int8
    const size_t need = th_bytes + (size_t)(NCYC + 1) * sizeof(int);
    if (ws_size >= need) {
        signed char* th = (signed char*)d_ws;
        int* row_start  = (int*)(th + th_bytes);

        const float4* c4 = (const float4*)c;
        const float4* s4 = (const float4*)s;
        void* args[] = {(void*)&c4, (void*)&s4, (void*)&th, (void*)&row_start,
                        (void*)&cysigns, (void*)&cyinds, (void*)&cyrows,
                        (void*)&E, (void*)&out};
        hipLaunchCooperativeKernel((void*)fused_k, dim3(GRID_F), dim3(256),
                                   args, 0, stream);
    } else {
        zero_out_k<<<1, 64, 0, stream>>>(out);
        kvl_fallback_k<<<NCYC, 256, 0, stream>>>(c, s, cysigns, cyinds, cyrows, E, out);
    }
}

// Round 4
// 255.394 us; speedup vs baseline: 1.0114x; 1.0114x over previous
//
#include <hip/hip_runtime.h>

#define NB     50000
#define NB4    12500
#define BATCH  256
#define NCYC   20000
#define QSCALE  (127.0f / 3.14159265358979f)
#define DQSCALE (3.14159265358979f / 127.0f)
#define OUTSCALE (1.0f / ((float)NCYC * (float)BATCH))

// Fast atan2: Hastings deg-9 odd minimax on [0,1], max err ~1e-5 rad.
// Quantization step is pi/127 ~ 2.47e-2 rad; ~4e-4 of elements can flip one
// int8 code => ~1e-7 relative error on the final mean.
__device__ __forceinline__ float fast_atan2f(float y, float x) {
    const float ax = __builtin_fabsf(x);
    const float ay = __builtin_fabsf(y);
    const float mx = fmaxf(ax, ay);
    const float mn = fminf(ax, ay);
    const float t  = mn * __builtin_amdgcn_rcpf(mx);   // in [0,1]
    const float t2 = t * t;
    float p = fmaf(t2, fmaf(t2, fmaf(t2, fmaf(t2,
                  0.0208351f, -0.0851330f), 0.1801410f), -0.3302995f),
                  0.9998660f);
    p *= t;
    p = (ay > ax) ? (1.57079632679489662f - p) : p;    // swap quadrant
    p = (x < 0.0f) ? (3.14159265358979324f - p) : p;   // left half-plane
    return copysignf(p, y);
}

// ---- kernel 1: transpose + atan2 + int8 quantize -> th[NB][BATCH],
//      plus fully-parallel row_start precompute + counter init ------------
__global__ __launch_bounds__(256) void theta_k(
        const float4* __restrict__ c4, const float4* __restrict__ s4,
        signed char* __restrict__ th, int* __restrict__ row_start,
        const int* __restrict__ rows, int E, int* __restrict__ counter) {
    __shared__ signed char t[64][68];       // [b_local][nb_local], 68 = 4*17
    const int u = threadIdx.x;

    if (blockIdx.x == 0 && blockIdx.y == 0 && u == 0) *counter = 0;

    // row_start[0..NCYC]: one binary search per thread, hidden under the
    // memory-bound theta work (rows = 640 KB, L2-resident).
    if (blockIdx.y == 0) {
        const int g = blockIdx.x * 256 + u;
        if (g <= NCYC) {
            int lo = 0, hi = E;
            while (lo < hi) { const int m = (lo + hi) >> 1; if (rows[m] < g) lo = m + 1; else hi = m; }
            row_start[g] = lo;
        }
    }

    const int col4 = u & 15;                // nb4 within tile
    const int brow = u >> 4;                // 0..15
    const int x4   = blockIdx.x * 16 + col4;
    const int bb   = blockIdx.y * 64;

    if (x4 < NB4) {
        #pragma unroll
        for (int j = 0; j < 4; ++j) {
            const int bl = brow + 16 * j;   // b_local 0..63
            const float4 vc = c4[(size_t)(bb + bl) * NB4 + x4];
            const float4 vs = s4[(size_t)(bb + bl) * NB4 + x4];
            char4 q;
            q.x = (signed char)__float2int_rn(fast_atan2f(vs.x, vc.x) * QSCALE);
            q.y = (signed char)__float2int_rn(fast_atan2f(vs.y, vc.y) * QSCALE);
            q.z = (signed char)__float2int_rn(fast_atan2f(vs.z, vc.z) * QSCALE);
            q.w = (signed char)__float2int_rn(fast_atan2f(vs.w, vc.w) * QSCALE);
            *reinterpret_cast<char4*>(&t[bl][4 * col4]) = q;
        }
    }
    __syncthreads();
    // store phase: 16 lanes cover 64 consecutive b (64B) per nb
    const int g   = u & 15;                 // char4 group along b
    const int nb0 = u >> 4;                 // 0..15
    #pragma unroll
    for (int j = 0; j < 4; ++j) {
        const int nbl = nb0 + 16 * j;       // 0..63
        const int nb  = blockIdx.x * 64 + nbl;
        if (nb < NB) {
            char4 v;
            v.x = t[4 * g + 0][nbl];
            v.y = t[4 * g + 1][nbl];
            v.z = t[4 * g + 2][nbl];
            v.w = t[4 * g + 3][nbl];
            *reinterpret_cast<char4*>(&th[(size_t)nb * BATCH + bb + 4 * g]) = v;
        }
    }
}

// ---- kernel 2: wave per row (4/block), precomputed bounds, last-block
//      reduction of the 5000 block partials -> out ------------------------
__global__ __launch_bounds__(256) void kvl2_k(
        const signed char* __restrict__ th,
        const float* __restrict__ signs, const int* __restrict__ inds,
        const int* __restrict__ row_start,
        float* __restrict__ partials, int* __restrict__ counter,
        float* __restrict__ out) {
    __shared__ float wsum[4];
    __shared__ int   lastflag;
    const int tid  = threadIdx.x;
    const int wave = tid >> 6;
    const int lane = tid & 63;
    const int r    = blockIdx.x * 4 + wave;           // < NCYC (5000*4)
    const int start = row_start[r];
    const int end   = row_start[r + 1];

    float a0 = 0.f, a1 = 0.f, a2 = 0.f, a3 = 0.f;
    int e = start;
    for (; e + 2 <= end; e += 2) {
        const int   i0 = inds[e],  i1 = inds[e + 1];
        const float g0 = signs[e] * DQSCALE, g1 = signs[e + 1] * DQSCALE;
        const unsigned int u0 = *reinterpret_cast<const unsigned int*>(&th[(size_t)i0 * BATCH + lane * 4]);
        const unsigned int u1 = *reinterpret_cast<const unsigned int*>(&th[(size_t)i1 * BATCH + lane * 4]);
        a0 += g0 * (float)(signed char)(u0      ) + g1 * (float)(signed char)(u1      );
        a1 += g0 * (float)(signed char)(u0 >>  8) + g1 * (float)(signed char)(u1 >>  8);
        a2 += g0 * (float)(signed char)(u0 >> 16) + g1 * (float)(signed char)(u1 >> 16);
        a3 += g0 * (float)(signed char)(u0 >> 24) + g1 * (float)(signed char)(u1 >> 24);
    }
    if (e < end) {
        const float g0 = signs[e] * DQSCALE;
        const unsigned int u0 = *reinterpret_cast<const unsigned int*>(&th[(size_t)inds[e] * BATCH + lane * 4]);
        a0 += g0 * (float)(signed char)(u0      );
        a1 += g0 * (float)(signed char)(u0 >>  8);
        a2 += g0 * (float)(signed char)(u0 >> 16);
        a3 += g0 * (float)(signed char)(u0 >> 24);
    }
    float v = fabsf(a0) + fabsf(a1) + fabsf(a2) + fabsf(a3);
    #pragma unroll
    for (int off = 32; off > 0; off >>= 1)
        v += __shfl_down(v, off, 64);
    if (lane == 0) wsum[wave] = v;
    __syncthreads();

    if (tid == 0) {
        partials[blockIdx.x] = wsum[0] + wsum[1] + wsum[2] + wsum[3];
        __threadfence();                                   // release partial
        const int ticket = atomicAdd(counter, 1);
        lastflag = (ticket == gridDim.x - 1) ? 1 : 0;
    }
    __syncthreads();

    if (lastflag) {
        __threadfence();                                   // acquire partials
        float acc = 0.f;
        for (int i = tid; i < (int)gridDim.x; i += 256) acc += partials[i];
        #pragma unroll
        for (int off = 32; off > 0; off >>= 1)
            acc += __shfl_down(acc, off, 64);
        if (lane == 0) wsum[wave] = acc;
        __syncthreads();
        if (tid == 0)
            out[0] = (wsum[0] + wsum[1] + wsum[2] + wsum[3]) * OUTSCALE;
    }
}

// ---- fallback (no workspace): direct strided gather -----------------------
__global__ void zero_out_k(float* out) { if (threadIdx.x == 0) out[0] = 0.0f; }

__global__ __launch_bounds__(256) void kvl_fallback_k(
        const float* __restrict__ c, const float* __restrict__ s,
        const float* __restrict__ signs, const int* __restrict__ inds,
        const int* __restrict__ rows, int E, float* __restrict__ out) {
    const int r = blockIdx.x;
    int lo = 0, hi = E;
    while (lo < hi) { const int m = (lo + hi) >> 1; if (rows[m] < r) lo = m + 1; else hi = m; }
    const int start = lo;
    hi = E;
    while (lo < hi) { const int m = (lo + hi) >> 1; if (rows[m] <= r) lo = m + 1; else hi = m; }
    const int end = lo;
    const int tid = threadIdx.x;
    float acc = 0.f;
    for (int e = start; e < end; ++e) {
        const int idx = inds[e];
        const float sg = signs[e];
        acc += atan2f(sg * s[(size_t)tid * NB + idx], c[(size_t)tid * NB + idx]);
    }
    float v = fabsf(acc);
    #pragma unroll
    for (int off = 32; off > 0; off >>= 1)
        v += __shfl_down(v, off, 64);
    __shared__ float wsum[4];
    if ((tid & 63) == 0) wsum[tid >> 6] = v;
    __syncthreads();
    if (tid == 0)
        atomicAdd(out, (wsum[0] + wsum[1] + wsum[2] + wsum[3]) *
                       (1.0f / ((float)NCYC * (float)BATCH)));
}

extern "C" void kernel_launch(void* const* d_in, const int* in_sizes, int n_in,
                              void* d_out, int out_size, void* d_ws, size_t ws_size,
                              hipStream_t stream) {
    const float* c       = (const float*)d_in[0];
    const float* s       = (const float*)d_in[1];
    const float* cysigns = (const float*)d_in[2];
    const int*   cyinds  = (const int*)d_in[3];
    const int*   cyrows  = (const int*)d_in[4];
    const int    E       = in_sizes[2];   // 160000
    float* out = (float*)d_out;

    const size_t th_bytes = (size_t)NB * BATCH;            // 12.8 MB int8
    const size_t rs_bytes = (size_t)(NCYC + 1) * sizeof(int);
    const size_t pa_bytes = (size_t)(NCYC / 4) * sizeof(float);
    const size_t need = th_bytes + rs_bytes + pa_bytes + sizeof(int);
    if (ws_size >= need) {
        signed char* th   = (signed char*)d_ws;
        int* row_start    = (int*)(th + th_bytes);
        float* partials   = (float*)((char*)row_start + rs_bytes);
        int* counter      = (int*)((char*)partials + pa_bytes);

        dim3 tg((NB4 + 15) / 16, BATCH / 64);              // (782, 4)
        theta_k<<<tg, 256, 0, stream>>>((const float4*)c, (const float4*)s,
                                        th, row_start, cyrows, E, counter);
        kvl2_k<<<NCYC / 4, 256, 0, stream>>>(th, cysigns, cyinds, row_start,
                                             partials, counter, out);
    } else {
        zero_out_k<<<1, 64, 0, stream>>>(out);
        kvl_fallback_k<<<NCYC, 256, 0, stream>>>(c, s, cysigns, cyinds, cyrows, E, out);
    }
}

// Round 5
// 147.787 us; speedup vs baseline: 1.7478x; 1.7281x over previous
//
#include <hip/hip_runtime.h>

#define NB     50000
#define NB4    12500
#define BATCH  256
#define NCYC   20000
#define QSCALE  (127.0f / 3.14159265358979f)
#define DQSCALE (3.14159265358979f / 127.0f)
#define OUTSCALE (1.0f / ((float)NCYC * (float)BATCH))

// Fast atan2: Hastings deg-9 odd minimax on [0,1], max err ~1e-5 rad.
// Quantization step is pi/127 ~ 2.47e-2 rad; ~4e-4 of elements can flip one
// int8 code => ~1e-7 relative error on the final mean.
__device__ __forceinline__ float fast_atan2f(float y, float x) {
    const float ax = __builtin_fabsf(x);
    const float ay = __builtin_fabsf(y);
    const float mx = fmaxf(ax, ay);
    const float mn = fminf(ax, ay);
    const float t  = mn * __builtin_amdgcn_rcpf(mx);   // in [0,1]
    const float t2 = t * t;
    float p = fmaf(t2, fmaf(t2, fmaf(t2, fmaf(t2,
                  0.0208351f, -0.0851330f), 0.1801410f), -0.3302995f),
                  0.9998660f);
    p *= t;
    p = (ay > ax) ? (1.57079632679489662f - p) : p;    // swap quadrant
    p = (x < 0.0f) ? (3.14159265358979324f - p) : p;   // left half-plane
    return copysignf(p, y);
}

// ---- kernel 1: transpose + atan2 + int8 quantize -> th[NB][BATCH],
//      plus fully-parallel row_start precompute (hidden under mem-bound
//      theta work; rows = 640 KB, L2-resident). NO fences, NO counters. ----
__global__ __launch_bounds__(256) void theta_k(
        const float4* __restrict__ c4, const float4* __restrict__ s4,
        signed char* __restrict__ th, int* __restrict__ row_start,
        const int* __restrict__ rows, int E) {
    __shared__ signed char t[64][68];       // [b_local][nb_local], 68 = 4*17
    const int u = threadIdx.x;

    if (blockIdx.y == 0) {
        const int g = blockIdx.x * 256 + u;
        if (g <= NCYC) {
            int lo = 0, hi = E;
            while (lo < hi) { const int m = (lo + hi) >> 1; if (rows[m] < g) lo = m + 1; else hi = m; }
            row_start[g] = lo;
        }
    }

    const int col4 = u & 15;                // nb4 within tile
    const int brow = u >> 4;                // 0..15
    const int x4   = blockIdx.x * 16 + col4;
    const int bb   = blockIdx.y * 64;

    if (x4 < NB4) {
        #pragma unroll
        for (int j = 0; j < 4; ++j) {
            const int bl = brow + 16 * j;   // b_local 0..63
            const float4 vc = c4[(size_t)(bb + bl) * NB4 + x4];
            const float4 vs = s4[(size_t)(bb + bl) * NB4 + x4];
            char4 q;
            q.x = (signed char)__float2int_rn(fast_atan2f(vs.x, vc.x) * QSCALE);
            q.y = (signed char)__float2int_rn(fast_atan2f(vs.y, vc.y) * QSCALE);
            q.z = (signed char)__float2int_rn(fast_atan2f(vs.z, vc.z) * QSCALE);
            q.w = (signed char)__float2int_rn(fast_atan2f(vs.w, vc.w) * QSCALE);
            *reinterpret_cast<char4*>(&t[bl][4 * col4]) = q;
        }
    }
    __syncthreads();
    // store phase: 16 lanes cover 64 consecutive b (64B) per nb
    const int g   = u & 15;                 // char4 group along b
    const int nb0 = u >> 4;                 // 0..15
    #pragma unroll
    for (int j = 0; j < 4; ++j) {
        const int nbl = nb0 + 16 * j;       // 0..63
        const int nb  = blockIdx.x * 64 + nbl;
        if (nb < NB) {
            char4 v;
            v.x = t[4 * g + 0][nbl];
            v.y = t[4 * g + 1][nbl];
            v.z = t[4 * g + 2][nbl];
            v.w = t[4 * g + 3][nbl];
            *reinterpret_cast<char4*>(&th[(size_t)nb * BATCH + bb + 4 * g]) = v;
        }
    }
}

// ---- kernel 2: wave per row (4/block), precomputed bounds, NO fences,
//      one partial per block ----------------------------------------------
__global__ __launch_bounds__(256) void kvl3_k(
        const signed char* __restrict__ th,
        const float* __restrict__ signs, const int* __restrict__ inds,
        const int* __restrict__ row_start,
        float* __restrict__ partials) {
    __shared__ float wsum[4];
    const int tid  = threadIdx.x;
    const int wave = tid >> 6;
    const int lane = tid & 63;
    const int r    = blockIdx.x * 4 + wave;           // < NCYC (5000*4)
    const int start = row_start[r];
    const int end   = row_start[r + 1];

    float a0 = 0.f, a1 = 0.f, a2 = 0.f, a3 = 0.f;
    int e = start;
    for (; e + 2 <= end; e += 2) {
        const int   i0 = inds[e],  i1 = inds[e + 1];
        const float g0 = signs[e] * DQSCALE, g1 = signs[e + 1] * DQSCALE;
        const unsigned int u0 = *reinterpret_cast<const unsigned int*>(&th[(size_t)i0 * BATCH + lane * 4]);
        const unsigned int u1 = *reinterpret_cast<const unsigned int*>(&th[(size_t)i1 * BATCH + lane * 4]);
        a0 += g0 * (float)(signed char)(u0      ) + g1 * (float)(signed char)(u1      );
        a1 += g0 * (float)(signed char)(u0 >>  8) + g1 * (float)(signed char)(u1 >>  8);
        a2 += g0 * (float)(signed char)(u0 >> 16) + g1 * (float)(signed char)(u1 >> 16);
        a3 += g0 * (float)(signed char)(u0 >> 24) + g1 * (float)(signed char)(u1 >> 24);
    }
    if (e < end) {
        const float g0 = signs[e] * DQSCALE;
        const unsigned int u0 = *reinterpret_cast<const unsigned int*>(&th[(size_t)inds[e] * BATCH + lane * 4]);
        a0 += g0 * (float)(signed char)(u0      );
        a1 += g0 * (float)(signed char)(u0 >>  8);
        a2 += g0 * (float)(signed char)(u0 >> 16);
        a3 += g0 * (float)(signed char)(u0 >> 24);
    }
    float v = fabsf(a0) + fabsf(a1) + fabsf(a2) + fabsf(a3);
    #pragma unroll
    for (int off = 32; off > 0; off >>= 1)
        v += __shfl_down(v, off, 64);
    if (lane == 0) wsum[wave] = v;
    __syncthreads();
    if (tid == 0)
        partials[blockIdx.x] = wsum[0] + wsum[1] + wsum[2] + wsum[3];
}

// ---- kernel 3: single block reduces 5000 block partials -> out[0] ---------
__global__ __launch_bounds__(1024) void reduce_k(
        const float* __restrict__ partials, float* __restrict__ out) {
    const int tid = threadIdx.x;
    float v = 0.f;
    for (int i = tid; i < NCYC / 4; i += 1024) v += partials[i];
    #pragma unroll
    for (int off = 32; off > 0; off >>= 1)
        v += __shfl_down(v, off, 64);
    __shared__ float wsum[16];
    if ((tid & 63) == 0) wsum[tid >> 6] = v;
    __syncthreads();
    if (tid == 0) {
        float t = 0.f;
        #pragma unroll
        for (int w = 0; w < 16; ++w) t += wsum[w];
        out[0] = t * OUTSCALE;
    }
}

// ---- fallback (no workspace): direct strided gather -----------------------
__global__ void zero_out_k(float* out) { if (threadIdx.x == 0) out[0] = 0.0f; }

__global__ __launch_bounds__(256) void kvl_fallback_k(
        const float* __restrict__ c, const float* __restrict__ s,
        const float* __restrict__ signs, const int* __restrict__ inds,
        const int* __restrict__ rows, int E, float* __restrict__ out) {
    const int r = blockIdx.x;
    int lo = 0, hi = E;
    while (lo < hi) { const int m = (lo + hi) >> 1; if (rows[m] < r) lo = m + 1; else hi = m; }
    const int start = lo;
    hi = E;
    while (lo < hi) { const int m = (lo + hi) >> 1; if (rows[m] <= r) lo = m + 1; else hi = m; }
    const int end = lo;
    const int tid = threadIdx.x;
    float acc = 0.f;
    for (int e = start; e < end; ++e) {
        const int idx = inds[e];
        const float sg = signs[e];
        acc += atan2f(sg * s[(size_t)tid * NB + idx], c[(size_t)tid * NB + idx]);
    }
    float v = fabsf(acc);
    #pragma unroll
    for (int off = 32; off > 0; off >>= 1)
        v += __shfl_down(v, off, 64);
    __shared__ float wsum[4];
    if ((tid & 63) == 0) wsum[tid >> 6] = v;
    __syncthreads();
    if (tid == 0)
        atomicAdd(out, (wsum[0] + wsum[1] + wsum[2] + wsum[3]) *
                       (1.0f / ((float)NCYC * (float)BATCH)));
}

extern "C" void kernel_launch(void* const* d_in, const int* in_sizes, int n_in,
                              void* d_out, int out_size, void* d_ws, size_t ws_size,
                              hipStream_t stream) {
    const float* c       = (const float*)d_in[0];
    const float* s       = (const float*)d_in[1];
    const float* cysigns = (const float*)d_in[2];
    const int*   cyinds  = (const int*)d_in[3];
    const int*   cyrows  = (const int*)d_in[4];
    const int    E       = in_sizes[2];   // 160000
    float* out = (float*)d_out;

    const size_t th_bytes = (size_t)NB * BATCH;            // 12.8 MB int8
    const size_t rs_bytes = (size_t)(NCYC + 1) * sizeof(int);
    const size_t pa_bytes = (size_t)(NCYC / 4) * sizeof(float);
    const size_t need = th_bytes + rs_bytes + pa_bytes;
    if (ws_size >= need) {
        signed char* th   = (signed char*)d_ws;
        int* row_start    = (int*)(th + th_bytes);
        float* partials   = (float*)((char*)row_start + rs_bytes);

        dim3 tg((NB4 + 15) / 16, BATCH / 64);              // (782, 4)
        theta_k<<<tg, 256, 0, stream>>>((const float4*)c, (const float4*)s,
                                        th, row_start, cyrows, E);
        kvl3_k<<<NCYC / 4, 256, 0, stream>>>(th, cysigns, cyinds, row_start,
                                             partials);
        reduce_k<<<1, 1024, 0, stream>>>(partials, out);
    } else {
        zero_out_k<<<1, 64, 0, stream>>>(out);
        kvl_fallback_k<<<NCYC, 256, 0, stream>>>(c, s, cysigns, cyinds, cyrows, E, out);
    }
}